// Round 9
// baseline (107.839 us; speedup 1.0000x reference)
//
#include <hip/hip_runtime.h>
#include <stdint.h>

#define NT 2048
#define DT 128

typedef __bf16 bf16x8 __attribute__((ext_vector_type(8)));
typedef __bf16 bf16x4 __attribute__((ext_vector_type(4)));
typedef float  f32x16 __attribute__((ext_vector_type(16)));
typedef uint32_t u32x4 __attribute__((ext_vector_type(4)));

static __device__ __forceinline__ uint32_t pk2(float lo, float hi) {
    union { __bf16 h[2]; uint32_t u; } un;
    un.h[0] = (__bf16)lo; un.h[1] = (__bf16)hi;
    return un.u;
}

// v_permlane32_swap_b32: x' = {x.lo32, y.lo32}, y' = {x.hi32, y.hi32}.
// s_nop guards for VALU->permlane and permlane->MFMA hazard windows.
static __device__ __forceinline__ void lane32_swap(uint32_t& x, uint32_t& y) {
    asm("s_nop 0\n\tv_permlane32_swap_b32 %0, %1\n\ts_nop 1"
        : "+v"(x), "+v"(y));
}

// ============================================================================
// prep2: convert Q,K,V fp32 into MFMA-FRAGMENT-ORDER bf16 buffers so every
// fragment load downstream is one coalesced 1KB wave-load.
//   Qf[b][c][k][l][j] = Q[b][d=16k+8*(l>>5)+j][n=32c+(l&31)]     (4 MB)
//   Kf[b][mc][k][l][j] = K[b][d=16k+8*(l>>5)+j][m=32mc+(l&31)]   (4 MB)
//   Vf[b][c][vc][kk][l][j] = V[b][v=32vc+(l&31)][n=32c+16kk+8*(l>>5)+j] (4 MB)
// ============================================================================
__global__ __launch_bounds__(256)
void prep2(const float* __restrict__ Q, const float* __restrict__ K,
           const float* __restrict__ V,
           __bf16* __restrict__ Qf, __bf16* __restrict__ Kf, __bf16* __restrict__ Vf)
{
    const int bid = blockIdx.x;
    const int t   = threadIdx.x;
    if (bid < 512) {
        __shared__ float ls[128][65];
        const int which = bid >> 8;            // 0=Q, 1=K
        const float* src = which ? K : Q;
        __bf16*      dst = which ? Kf : Qf;
        const int idx = bid & 255;
        const int b   = idx >> 5;              // 0..7
        const int ct  = idx & 31;              // 64-wide n/m tile
        const int n0  = ct * 64;
        const float* sb = src + (size_t)b * DT * NT;
        #pragma unroll
        for (int rr = 0; rr < 8; ++rr) {
            const int d = (t >> 4) + 16 * rr;
            const float4 v4 = *(const float4*)(sb + (size_t)d * NT + n0 + 4 * (t & 15));
            ls[d][4 * (t & 15) + 0] = v4.x;
            ls[d][4 * (t & 15) + 1] = v4.y;
            ls[d][4 * (t & 15) + 2] = v4.z;
            ls[d][4 * (t & 15) + 3] = v4.w;
        }
        __syncthreads();
        const int l  = t & 63;
        const int kq = t >> 6;                 // 0..3
        const int lq = l >> 5, l31 = l & 31;
        #pragma unroll
        for (int c = 0; c < 2; ++c) {
            #pragma unroll
            for (int kh = 0; kh < 2; ++kh) {
                const int k = kq + 4 * kh;
                bf16x8 f;
                #pragma unroll
                for (int j = 0; j < 8; ++j)
                    f[j] = (__bf16)ls[16 * k + 8 * lq + j][32 * c + l31];
                *(bf16x8*)(dst + ((size_t)((b * 64 + 2 * ct + c) * 8 + k)) * 512 + l * 8) = f;
            }
        }
    } else {
        const int idx = bid - 512;             // 0..255
        const int b   = idx >> 5;
        const int cg  = idx & 31;
        const int l   = t & 63;
        const int vc  = t >> 6;                // 0..3
        const int lq  = l >> 5, l31 = l & 31;
        const float* vsrc = V + (size_t)b * DT * NT;
        #pragma unroll
        for (int ci = 0; ci < 2; ++ci) {
            const int c = 2 * cg + ci;
            #pragma unroll
            for (int kk = 0; kk < 2; ++kk) {
                const float* p = vsrc + (size_t)(32 * vc + l31) * NT + 32 * c + 16 * kk + 8 * lq;
                const float4 x = *(const float4*)p;
                const float4 y = *(const float4*)(p + 4);
                bf16x8 f;
                f[0] = (__bf16)x.x; f[1] = (__bf16)x.y; f[2] = (__bf16)x.z; f[3] = (__bf16)x.w;
                f[4] = (__bf16)y.x; f[5] = (__bf16)y.y; f[6] = (__bf16)y.z; f[7] = (__bf16)y.w;
                *(bf16x8*)(Vf + ((size_t)((b * 64 + c) * 4 + vc) * 2 + kk) * 512 + l * 8) = f;
            }
        }
    }
}

// ============================================================================
// sig_attn10: NO PARTIALS, NO REDUCE KERNEL, NO ATOMICS, NO OUT MEMSET.
// Output is split along v (free separable dim) instead of n:
//   grid 256 = b(8) x mt(16) x vh(2); 512 thr = 8 waves = wm(4 m-cols) x
//   wn(2 n-halves). Each wave: attn6's HW-verified zero-LDS pipeline over its
//   32 chunks (n-half): Q depth-2 prefetch, GEMM1(it+1) issued before
//   sigmoid(it), permlane32 C->B exchange, V depth-1 prefetch. GEMM2 covers
//   this block's 64-v half (GEMM1 duplicated x2 across vh — cheap at 13%
//   MfmaUtil). End: one 32KB LDS exchange merges the two n-halves per
//   (wm,tv), then direct coalesced fp32 store to out. Exactly 1 block/CU.
//   mfma_f32_32x32x16_bf16 C/D: col=lane&31, row=(reg&3)+8*(reg>>2)+4*(lane>>5)
// ============================================================================
__global__ __launch_bounds__(512, 2)
void sig_attn10(const __bf16* __restrict__ Qf, const __bf16* __restrict__ Kf,
                const __bf16* __restrict__ Vf, float* __restrict__ outp)
{
    __shared__ __align__(16) float xch[8][4][64][4];   // 32KB end-exchange

    const int t   = threadIdx.x;
    const int w   = t >> 6;       // wave 0..7
    const int l   = t & 63;
    const int lq  = l >> 5;
    const int l31 = l & 31;
    const int wm  = w & 3;        // m-column
    const int wn  = w >> 2;       // n-half

    const int bid = blockIdx.x;
    const int b   = bid & 7;             // XCD-pinned batch
    const int mt  = (bid >> 3) & 15;
    const int vh  = bid >> 7;            // 0..1 v-half

    const int m_blk = mt * 128;
    const int mrow  = 32 * wm + l31;

    // ---- K B-frags for this wave's m-column (coalesced 1KB loads)
    const __bf16* kfp = Kf + ((size_t)((b * 64 + 4 * mt + wm) * 8)) * 512 + l * 8;
    bf16x8 kf[8];
    #pragma unroll
    for (int k = 0; k < 8; ++k) kf[k] = *(const bf16x8*)(kfp + (size_t)k * 512);

    // chunk bases for this wave's n-half (32 chunks of 32 n)
    const __bf16* qb = Qf + ((size_t)(b * 64 + wn * 32) * 8) * 512 + l * 8;
    const __bf16* vb = Vf + (((size_t)(b * 64 + wn * 32) * 8) + 4 * vh) * 512 + l * 8;

    f32x16 oacc[2];   // tv 0,1 -> v = 64*vh + 32*tv + rowbits
    #pragma unroll
    for (int tv = 0; tv < 2; ++tv)
        #pragma unroll
        for (int r = 0; r < 16; ++r) oacc[tv][r] = 0.0f;

    // ---- prologue: Q frags chunks 0,1; V frags chunk 0; scores chunk 0
    bf16x8 qfA[8], qfB[8], av[4];
    #pragma unroll
    for (int k = 0; k < 8; ++k) qfA[k] = *(const bf16x8*)(qb + (size_t)k * 512);
    #pragma unroll
    for (int k = 0; k < 8; ++k) qfB[k] = *(const bf16x8*)(qb + (size_t)(8 + k) * 512);
    #pragma unroll
    for (int q = 0; q < 4; ++q) av[q] = *(const bf16x8*)(vb + (size_t)q * 512);

    f32x16 sA, sB;
    #pragma unroll
    for (int r = 0; r < 16; ++r) sA[r] = 0.0f;
    #pragma unroll
    for (int k = 0; k < 8; ++k)
        sA = __builtin_amdgcn_mfma_f32_32x32x16_bf16(qfA[k], kf[k], sA, 0, 0, 0);

    // body(it): SCUR = scores(it); QNXT = Q(it+1); av = V(it); QCUR<-Q(it+2);
    //           av<-V(it+1) after GEMM2 releases it.
    auto body = [&](f32x16& SCUR, f32x16& SNXT,
                    bf16x8 (&QCUR)[8], bf16x8 (&QNXT)[8], int it_) {
        if (it_ < 30) {
            const __bf16* qn = qb + (size_t)(it_ + 2) * 8 * 512;
            #pragma unroll
            for (int k = 0; k < 8; ++k) QCUR[k] = *(const bf16x8*)(qn + (size_t)k * 512);
        }
        if (it_ < 31) {
            #pragma unroll
            for (int r = 0; r < 16; ++r) SNXT[r] = 0.0f;
            #pragma unroll
            for (int k = 0; k < 8; ++k)
                SNXT = __builtin_amdgcn_mfma_f32_32x32x16_bf16(QNXT[k], kf[k], SNXT, 0, 0, 0);
        }

        float p[16];
        #pragma unroll
        for (int r = 0; r < 16; ++r) {
            const float e = __expf(SCUR[r] * -0.08838834764831845f);
            p[r] = __builtin_amdgcn_rcpf(1.0f + e);
        }

        uint32_t e0 = pk2(p[0],  p[1]),  e1 = pk2(p[2],  p[3]);
        uint32_t e2 = pk2(p[4],  p[5]),  e3 = pk2(p[6],  p[7]);
        uint32_t g0 = pk2(p[8],  p[9]),  g1 = pk2(p[10], p[11]);
        uint32_t g2 = pk2(p[12], p[13]), g3 = pk2(p[14], p[15]);
        lane32_swap(e0, e2);
        lane32_swap(e1, e3);
        lane32_swap(g0, g2);
        lane32_swap(g1, g3);
        u32x4 f0, f1;
        f0[0] = e0; f0[1] = e1; f0[2] = e2; f0[3] = e3;
        f1[0] = g0; f1[1] = g1; f1[2] = g2; f1[3] = g3;
        const bf16x8 bs0 = __builtin_bit_cast(bf16x8, f0);
        const bf16x8 bs1 = __builtin_bit_cast(bf16x8, f1);

        oacc[0] = __builtin_amdgcn_mfma_f32_32x32x16_bf16(av[0], bs0, oacc[0], 0, 0, 0);
        oacc[0] = __builtin_amdgcn_mfma_f32_32x32x16_bf16(av[1], bs1, oacc[0], 0, 0, 0);
        oacc[1] = __builtin_amdgcn_mfma_f32_32x32x16_bf16(av[2], bs0, oacc[1], 0, 0, 0);
        oacc[1] = __builtin_amdgcn_mfma_f32_32x32x16_bf16(av[3], bs1, oacc[1], 0, 0, 0);

        if (it_ < 31) {
            const __bf16* vn = vb + (size_t)(it_ + 1) * 8 * 512;
            #pragma unroll
            for (int q = 0; q < 4; ++q) av[q] = *(const bf16x8*)(vn + (size_t)q * 512);
        }
    };

    #pragma unroll 1
    for (int i2 = 0; i2 < 16; ++i2) {
        body(sA, sB, qfA, qfB, 2 * i2);
        body(sB, sA, qfB, qfA, 2 * i2 + 1);
    }

    // ---- merge n-halves: wave (wm,wn) gives tv=(wn^1), keeps tv=wn.
    // Static indexing in both branches (rule #20).
    if (wn == 0) {
        #pragma unroll
        for (int rq = 0; rq < 4; ++rq) {
            float4 g;
            g.x = oacc[1][4 * rq + 0]; g.y = oacc[1][4 * rq + 1];
            g.z = oacc[1][4 * rq + 2]; g.w = oacc[1][4 * rq + 3];
            *(float4*)&xch[w][rq][l][0] = g;
        }
    } else {
        #pragma unroll
        for (int rq = 0; rq < 4; ++rq) {
            float4 g;
            g.x = oacc[0][4 * rq + 0]; g.y = oacc[0][4 * rq + 1];
            g.z = oacc[0][4 * rq + 2]; g.w = oacc[0][4 * rq + 3];
            *(float4*)&xch[w][rq][l][0] = g;
        }
    }
    __syncthreads();
    const int pw = wm + 4 * (wn ^ 1);     // partner wave (other n-half)
    float* ob = outp + (size_t)b * DT * NT;
    if (wn == 0) {
        #pragma unroll
        for (int rq = 0; rq < 4; ++rq) {
            const float4 g = *(const float4*)&xch[pw][rq][l][0];
            oacc[0][4 * rq + 0] += g.x; oacc[0][4 * rq + 1] += g.y;
            oacc[0][4 * rq + 2] += g.z; oacc[0][4 * rq + 3] += g.w;
        }
        #pragma unroll
        for (int r = 0; r < 16; ++r) {
            const int v = 64 * vh + (r & 3) + 8 * (r >> 2) + 4 * lq;
            ob[(size_t)v * NT + m_blk + mrow] = oacc[0][r];
        }
    } else {
        #pragma unroll
        for (int rq = 0; rq < 4; ++rq) {
            const float4 g = *(const float4*)&xch[pw][rq][l][0];
            oacc[1][4 * rq + 0] += g.x; oacc[1][4 * rq + 1] += g.y;
            oacc[1][4 * rq + 2] += g.z; oacc[1][4 * rq + 3] += g.w;
        }
        #pragma unroll
        for (int r = 0; r < 16; ++r) {
            const int v = 64 * vh + 32 + (r & 3) + 8 * (r >> 2) + 4 * lq;
            ob[(size_t)v * NT + m_blk + mrow] = oacc[1][r];
        }
    }
}

// ============================================================================
// v1 kernel + reduce4 kept verbatim as fallback for small-ws harnesses
// ============================================================================
__global__ __launch_bounds__(256)
void reduce4(const float4* __restrict__ ws, float4* __restrict__ out)
{
    const int i = blockIdx.x * 256 + threadIdx.x;
    const int o = i * 4;
    const int m_glob = o & 2047;
    const int vb     = o >> 11;
    const int v      = vb & 127;
    const int bb     = vb >> 7;
    const int mt     = m_glob >> 7;
    const int m      = m_glob & 127;
    const size_t base = ((size_t)(bb + 8 * mt) * 16384 + (size_t)v * 128 + m) >> 2;
    const size_t strd = 524288;
    float4 a = ws[base];
    float4 c = ws[base + strd];
    float4 d = ws[base + 2 * strd];
    float4 e = ws[base + 3 * strd];
    float4 r;
    r.x = a.x + c.x + d.x + e.x;
    r.y = a.y + c.y + d.y + e.y;
    r.z = a.z + c.z + d.z + e.z;
    r.w = a.w + c.w + d.w + e.w;
    out[i] = r;
}

template <int WSMODE>
__global__ __launch_bounds__(512, 4)
void sig_attn(const float* __restrict__ Q, const float* __restrict__ K,
              const float* __restrict__ V, float* __restrict__ outp)
{
    __shared__ __align__(16) __bf16 Qs[64 * 128];
    __shared__ __align__(16) __bf16 Ss[128 * 64];
    __shared__ __align__(16) __bf16 Vs[2][128 * 64];

    const int t   = threadIdx.x;
    const int w   = t >> 6;
    const int l   = t & 63;
    const int lq  = l >> 5;
    const int l31 = l & 31;
    const int wm  = w & 3;
    const int wn  = w >> 2;

    const int bid    = blockIdx.x;
    const int b      = bid & 7;
    const int mt     = (bid >> 3) & 15;
    const int ns     = bid >> 7;
    const int m_blk  = mt * 128;
    const int n_base = ns * 512;

    const float* Qb = Q + (size_t)b * DT * NT;
    const float* Kb = K + (size_t)b * DT * NT;
    const float* Vb = V + (size_t)b * DT * NT;

    const int mrow = 32 * wm + l31;

    bf16x8 kf[8];
    #pragma unroll
    for (int half = 0; half < 2; ++half) {
        float tmp[4][8];
        #pragma unroll
        for (int k2 = 0; k2 < 4; ++k2)
            #pragma unroll
            for (int j = 0; j < 8; ++j)
                tmp[k2][j] = Kb[(size_t)((half * 4 + k2) * 16 + lq * 8 + j) * NT + m_blk + mrow];
        #pragma unroll
        for (int k2 = 0; k2 < 4; ++k2) {
            bf16x8 f;
            #pragma unroll
            for (int j = 0; j < 8; ++j) f[j] = (__bf16)tmp[k2][j];
            kf[half * 4 + k2] = f;
        }
    }

    f32x16 oacc[2];
    #pragma unroll
    for (int tv = 0; tv < 2; ++tv)
        #pragma unroll
        for (int r = 0; r < 16; ++r)
            oacc[tv][r] = 0.0f;

    float qp[16];
    #pragma unroll
    for (int r = 0; r < 2; ++r)
        #pragma unroll
        for (int j = 0; j < 8; ++j)
            qp[r * 8 + j] = Qb[(size_t)(64 * r + 8 * w + j) * NT + n_base + l];
    float4 vp[4];
    #pragma unroll
    for (int p = 0; p < 4; ++p)
        vp[p] = *(const float4*)(Vb + (size_t)(p * 32 + (t >> 4)) * NT + n_base + 4 * (t & 15));

    for (int it = 0; it < 8; ++it) {
        __bf16* Vbuf = Vs[it & 1];

        #pragma unroll
        for (int r = 0; r < 2; ++r) {
            bf16x8 pk;
            #pragma unroll
            for (int j = 0; j < 8; ++j) pk[j] = (__bf16)qp[r * 8 + j];
            *(bf16x8*)&Qs[l * 128 + ((8 * r + w) ^ (l & 15)) * 8] = pk;
        }
        #pragma unroll
        for (int p = 0; p < 4; ++p) {
            const int v  = p * 32 + (t >> 4);
            const int ng = t & 15;
            bf16x4 pk;
            pk[0] = (__bf16)vp[p].x;
            pk[1] = (__bf16)vp[p].y;
            pk[2] = (__bf16)vp[p].z;
            pk[3] = (__bf16)vp[p].w;
            *(bf16x4*)&Vbuf[v * 64 + ((ng >> 1) ^ (v & 7)) * 8 + 4 * (ng & 1)] = pk;
        }
        __syncthreads();

        const int n0n = n_base + ((it + 1) & 7) * 64;
        #pragma unroll
        for (int r = 0; r < 2; ++r)
            #pragma unroll
            for (int j = 0; j < 8; ++j)
                qp[r * 8 + j] = Qb[(size_t)(64 * r + 8 * w + j) * NT + n0n + l];
        #pragma unroll
        for (int p = 0; p < 4; ++p)
            vp[p] = *(const float4*)(Vb + (size_t)(p * 32 + (t >> 4)) * NT + n0n + 4 * (t & 15));

        f32x16 sacc;
        #pragma unroll
        for (int r = 0; r < 16; ++r) sacc[r] = 0.0f;
        const int nrow = 32 * wn + l31;
        #pragma unroll
        for (int k = 0; k < 8; ++k) {
            const bf16x8 af =
                *(const bf16x8*)&Qs[nrow * 128 + ((2 * k + lq) ^ (nrow & 15)) * 8];
            sacc = __builtin_amdgcn_mfma_f32_32x32x16_bf16(af, kf[k], sacc, 0, 0, 0);
        }

        #pragma unroll
        for (int g = 0; g < 4; ++g) {
            bf16x4 pk;
            #pragma unroll
            for (int rr = 0; rr < 4; ++rr) {
                const float x = sacc[4 * g + rr];
                const float e = __expf(x * -0.08838834764831845f);
                pk[rr] = (__bf16)__builtin_amdgcn_rcpf(1.0f + e);
            }
            *(bf16x4*)&Ss[mrow * 64 + ((4 * wn + g) ^ (mrow & 7)) * 8 + 4 * lq] = pk;
        }
        __syncthreads();

        #pragma unroll
        for (int k = 0; k < 4; ++k) {
            const int sw = 2 * k + lq;
            const bf16x8 av0 =
                *(const bf16x8*)&Vbuf[(64 * wn + l31) * 64 + (sw ^ (l31 & 7)) * 8];
            const bf16x8 av1 =
                *(const bf16x8*)&Vbuf[(64 * wn + 32 + l31) * 64 + (sw ^ (l31 & 7)) * 8];
            const bf16x8 bs =
                *(const bf16x8*)&Ss[mrow * 64 + (sw ^ (mrow & 7)) * 8];
            oacc[0] = __builtin_amdgcn_mfma_f32_32x32x16_bf16(av0, bs, oacc[0], 0, 0, 0);
            oacc[1] = __builtin_amdgcn_mfma_f32_32x32x16_bf16(av1, bs, oacc[1], 0, 0, 0);
        }
    }

    if (WSMODE == 0) {
        float* wsb = outp + (size_t)bid * 16384;
        #pragma unroll
        for (int tv = 0; tv < 2; ++tv) {
            #pragma unroll
            for (int r = 0; r < 16; ++r) {
                const int v = 64 * wn + 32 * tv + (r & 3) + 8 * (r >> 2) + 4 * lq;
                wsb[v * 128 + mrow] = oacc[tv][r];
            }
        }
    } else {
        float* Ob = outp + (size_t)b * DT * NT;
        #pragma unroll
        for (int tv = 0; tv < 2; ++tv) {
            #pragma unroll
            for (int r = 0; r < 16; ++r) {
                const int v = 64 * wn + 32 * tv + (r & 3) + 8 * (r >> 2) + 4 * lq;
                atomicAdd(&Ob[(size_t)v * NT + m_blk + mrow], oacc[tv][r]);
            }
        }
    }
}

extern "C" void kernel_launch(void* const* d_in, const int* in_sizes, int n_in,
                              void* d_out, int out_size, void* d_ws, size_t ws_size,
                              hipStream_t stream) {
    (void)in_sizes; (void)n_in;
    const float* Q = (const float*)d_in[0];
    const float* K = (const float*)d_in[1];
    const float* V = (const float*)d_in[2];
    const size_t FRAGB = (size_t)2097152 * 2;              // 4 MB per operand buffer
    const size_t PARTF = (size_t)512 * 16384 * 4;          // fallback fp32 partials
    if (ws_size >= 3 * FRAGB) {                            // 12.6 MB (ws is 256 MiB)
        __bf16* Qf = (__bf16*)d_ws;
        __bf16* Kf = Qf + 2097152;
        __bf16* Vf = Kf + 2097152;
        prep2<<<dim3(768), dim3(256), 0, stream>>>(Q, K, V, Qf, Kf, Vf);
        sig_attn10<<<dim3(256), dim3(512), 0, stream>>>(Qf, Kf, Vf, (float*)d_out);
    } else if (ws_size >= PARTF) {
        sig_attn<0><<<dim3(512), dim3(512), 0, stream>>>(Q, K, V, (float*)d_ws);
        reduce4<<<dim3(2048), dim3(256), 0, stream>>>((const float4*)d_ws, (float4*)d_out);
    } else {
        hipMemsetAsync(d_out, 0, (size_t)out_size * sizeof(float), stream);
        sig_attn<1><<<dim3(512), dim3(512), 0, stream>>>(Q, K, V, (float*)d_out);
    }
}

// Round 10
// 100.744 us; speedup vs baseline: 1.0704x; 1.0704x over previous
//
#include <hip/hip_runtime.h>
#include <stdint.h>

#define NT 2048
#define DT 128

typedef __bf16 bf16x8 __attribute__((ext_vector_type(8)));
typedef __bf16 bf16x4 __attribute__((ext_vector_type(4)));
typedef float  f32x16 __attribute__((ext_vector_type(16)));
typedef uint32_t u32x4 __attribute__((ext_vector_type(4)));
typedef _Float16 f16;
typedef _Float16 f16x4 __attribute__((ext_vector_type(4)));

static __device__ __forceinline__ uint32_t pk2(float lo, float hi) {
    union { __bf16 h[2]; uint32_t u; } un;
    un.h[0] = (__bf16)lo; un.h[1] = (__bf16)hi;
    return un.u;
}

// v_permlane32_swap_b32: x' = {x.lo32, y.lo32}, y' = {x.hi32, y.hi32}.
// s_nop guards for VALU->permlane and permlane->MFMA hazard windows.
static __device__ __forceinline__ void lane32_swap(uint32_t& x, uint32_t& y) {
    asm("s_nop 0\n\tv_permlane32_swap_b32 %0, %1\n\ts_nop 1"
        : "+v"(x), "+v"(y));
}

// ============================================================================
// prep2: convert Q,K,V fp32 into MFMA-FRAGMENT-ORDER bf16 buffers so every
// fragment load downstream is one coalesced 1KB wave-load.
//   Qf[b][c][k][l][j] = Q[b][d=16k+8*(l>>5)+j][n=32c+(l&31)]     (4 MB)
//   Kf[b][mc][k][l][j] = K[b][d=16k+8*(l>>5)+j][m=32mc+(l&31)]   (4 MB)
//   Vf[b][c][vc][kk][l][j] = V[b][v=32vc+(l&31)][n=32c+16kk+8*(l>>5)+j] (4 MB)
// ============================================================================
__global__ __launch_bounds__(256)
void prep2(const float* __restrict__ Q, const float* __restrict__ K,
           const float* __restrict__ V,
           __bf16* __restrict__ Qf, __bf16* __restrict__ Kf, __bf16* __restrict__ Vf)
{
    const int bid = blockIdx.x;
    const int t   = threadIdx.x;
    if (bid < 512) {
        __shared__ float ls[128][65];
        const int which = bid >> 8;            // 0=Q, 1=K
        const float* src = which ? K : Q;
        __bf16*      dst = which ? Kf : Qf;
        const int idx = bid & 255;
        const int b   = idx >> 5;              // 0..7
        const int ct  = idx & 31;              // 64-wide n/m tile
        const int n0  = ct * 64;
        const float* sb = src + (size_t)b * DT * NT;
        #pragma unroll
        for (int rr = 0; rr < 8; ++rr) {
            const int d = (t >> 4) + 16 * rr;
            const float4 v4 = *(const float4*)(sb + (size_t)d * NT + n0 + 4 * (t & 15));
            ls[d][4 * (t & 15) + 0] = v4.x;
            ls[d][4 * (t & 15) + 1] = v4.y;
            ls[d][4 * (t & 15) + 2] = v4.z;
            ls[d][4 * (t & 15) + 3] = v4.w;
        }
        __syncthreads();
        const int l  = t & 63;
        const int kq = t >> 6;                 // 0..3
        const int lq = l >> 5, l31 = l & 31;
        #pragma unroll
        for (int c = 0; c < 2; ++c) {
            #pragma unroll
            for (int kh = 0; kh < 2; ++kh) {
                const int k = kq + 4 * kh;
                bf16x8 f;
                #pragma unroll
                for (int j = 0; j < 8; ++j)
                    f[j] = (__bf16)ls[16 * k + 8 * lq + j][32 * c + l31];
                *(bf16x8*)(dst + ((size_t)((b * 64 + 2 * ct + c) * 8 + k)) * 512 + l * 8) = f;
            }
        }
    } else {
        const int idx = bid - 512;             // 0..255
        const int b   = idx >> 5;
        const int cg  = idx & 31;
        const int l   = t & 63;
        const int vc  = t >> 6;                // 0..3
        const int lq  = l >> 5, l31 = l & 31;
        const float* vsrc = V + (size_t)b * DT * NT;
        #pragma unroll
        for (int ci = 0; ci < 2; ++ci) {
            const int c = 2 * cg + ci;
            #pragma unroll
            for (int kk = 0; kk < 2; ++kk) {
                const float* p = vsrc + (size_t)(32 * vc + l31) * NT + 32 * c + 16 * kk + 8 * lq;
                const float4 x = *(const float4*)p;
                const float4 y = *(const float4*)(p + 4);
                bf16x8 f;
                f[0] = (__bf16)x.x; f[1] = (__bf16)x.y; f[2] = (__bf16)x.z; f[3] = (__bf16)x.w;
                f[4] = (__bf16)y.x; f[5] = (__bf16)y.y; f[6] = (__bf16)y.z; f[7] = (__bf16)y.w;
                *(bf16x8*)(Vf + ((size_t)((b * 64 + c) * 4 + vc) * 2 + kk) * 512 + l * 8) = f;
            }
        }
    }
}

// ============================================================================
// sig_attn8h: round-7's best-measured attn kernel (DMA-LDS staging via
// global_load_lds width=16, one barrier per chunk, permlane32 exchange),
// VERBATIM except the epilogue writes fp16 partials (halves the partial
// write: 33.5 -> 16.8 MB).
//   mfma_f32_32x32x16_bf16 C/D: col=lane&31, row=(reg&3)+8*(reg>>2)+4*(lane>>5)
// ============================================================================
__global__ __launch_bounds__(256, 2)
void sig_attn8h(const __bf16* __restrict__ Qf, const __bf16* __restrict__ Kf,
                const __bf16* __restrict__ Vf, f16* __restrict__ wsp)
{
    __shared__ __align__(16) __bf16 buf[2][16384];   // 2 x 32KB

    const int t   = threadIdx.x;
    const int w   = t >> 6;       // wave 0..3 -> m-column
    const int l   = t & 63;
    const int lq  = l >> 5;
    const int l31 = l & 31;

    const int bid = blockIdx.x;
    const int b   = bid & 7;             // XCD-pinned batch
    const int mt  = (bid >> 3) & 15;
    const int ns  = bid >> 7;            // 0..3

    const int mrow = 32 * w + l31;       // local m within 128-tile

    // ---- K B-frags for this wave's m-column (per-wave distinct, stay global)
    const __bf16* kfp = Kf + ((size_t)((b * 64 + 4 * mt + w) * 8)) * 512 + l * 8;
    bf16x8 kf[8];
    #pragma unroll
    for (int k = 0; k < 8; ++k) kf[k] = *(const bf16x8*)(kfp + (size_t)k * 512);

    // chunk = 64 n: 16KB Q frags + 16KB V frags, both linear in fragment order
    const int c_base = ns * 16;
    const __bf16* qbase = Qf + ((size_t)(b * 64 + c_base) * 8) * 512;
    const __bf16* vbase = Vf + ((size_t)(b * 64 + c_base) * 8) * 512;

    f32x16 oacc[4];
    #pragma unroll
    for (int tv = 0; tv < 4; ++tv)
        #pragma unroll
        for (int r = 0; r < 16; ++r) oacc[tv][r] = 0.0f;

    // ---- staging: frag f (0..31) = 1KB; wave w DMAs frags 8w..8w+7.
    auto stage = [&](int it_, int cb) {
        #pragma unroll
        for (int p = 0; p < 8; ++p) {
            const int f = 8 * w + p;
            const __bf16* src = (f < 16)
                ? qbase + (size_t)it_ * 8192 + (size_t)f * 512 + l * 8
                : vbase + (size_t)it_ * 8192 + (size_t)(f - 16) * 512 + l * 8;
            __builtin_amdgcn_global_load_lds(
                (const __attribute__((address_space(1))) uint32_t*)src,
                (__attribute__((address_space(3))) uint32_t*)&buf[cb][f * 512],
                16, 0, 0);
        }
    };

    // ---- prologue: stage chunk 0 (barrier's vmcnt(0) drain covers completion)
    stage(0, 0);
    __syncthreads();

    #pragma unroll 1
    for (int it = 0; it < 8; ++it) {
        const int cb = it & 1;
        const __bf16* B = buf[cb];

        // -- DMA chunk it+1 into the other buffer (in flight across compute)
        if (it < 7) stage(it + 1, cb ^ 1);

        // -- GEMM1 sub0 and sub1 (all MFMAs issued before any sigmoid VALU)
        bf16x8 qf[8];
        f32x16 s0, s1;
        #pragma unroll
        for (int r = 0; r < 16; ++r) { s0[r] = 0.0f; s1[r] = 0.0f; }
        #pragma unroll
        for (int k = 0; k < 8; ++k) qf[k] = *(const bf16x8*)&B[(0 * 8 + k) * 512 + l * 8];
        #pragma unroll
        for (int k = 0; k < 8; ++k)
            s0 = __builtin_amdgcn_mfma_f32_32x32x16_bf16(qf[k], kf[k], s0, 0, 0, 0);
        #pragma unroll
        for (int k = 0; k < 8; ++k) qf[k] = *(const bf16x8*)&B[(1 * 8 + k) * 512 + l * 8];
        #pragma unroll
        for (int k = 0; k < 8; ++k)
            s1 = __builtin_amdgcn_mfma_f32_32x32x16_bf16(qf[k], kf[k], s1, 0, 0, 0);

        // -- per sub-chunk: sigmoid + permlane exchange + GEMM2
        #pragma unroll
        for (int sub = 0; sub < 2; ++sub) {
            const f32x16& S = sub ? s1 : s0;
            float p[16];
            #pragma unroll
            for (int r = 0; r < 16; ++r) {
                const float e = __expf(S[r] * -0.08838834764831845f);
                p[r] = __builtin_amdgcn_rcpf(1.0f + e);
            }
            uint32_t e0 = pk2(p[0],  p[1]),  e1 = pk2(p[2],  p[3]);
            uint32_t e2 = pk2(p[4],  p[5]),  e3 = pk2(p[6],  p[7]);
            uint32_t g0 = pk2(p[8],  p[9]),  g1 = pk2(p[10], p[11]);
            uint32_t g2 = pk2(p[12], p[13]), g3 = pk2(p[14], p[15]);
            lane32_swap(e0, e2);
            lane32_swap(e1, e3);
            lane32_swap(g0, g2);
            lane32_swap(g1, g3);
            u32x4 f0, f1;
            f0[0] = e0; f0[1] = e1; f0[2] = e2; f0[3] = e3;
            f1[0] = g0; f1[1] = g1; f1[2] = g2; f1[3] = g3;
            const bf16x8 bs0 = __builtin_bit_cast(bf16x8, f0);
            const bf16x8 bs1 = __builtin_bit_cast(bf16x8, f1);

            bf16x8 av[8];
            #pragma unroll
            for (int q = 0; q < 8; ++q)
                av[q] = *(const bf16x8*)&B[(16 + sub * 8 + q) * 512 + l * 8];
            #pragma unroll
            for (int tv = 0; tv < 4; ++tv) {
                oacc[tv] = __builtin_amdgcn_mfma_f32_32x32x16_bf16(av[2 * tv],     bs0, oacc[tv], 0, 0, 0);
                oacc[tv] = __builtin_amdgcn_mfma_f32_32x32x16_bf16(av[2 * tv + 1], bs1, oacc[tv], 0, 0, 0);
            }
        }

        __syncthreads();   // drains DMA (long in flight) + fences buffer reuse
    }

    // ---- epilogue: per-block fp16 partial [v 128][m 128]
    f16* wsb = wsp + (size_t)bid * 16384;
    #pragma unroll
    for (int tv = 0; tv < 4; ++tv) {
        #pragma unroll
        for (int r = 0; r < 16; ++r) {
            const int v = 32 * tv + (r & 3) + 8 * (r >> 2) + 4 * lq;
            wsb[v * 128 + mrow] = (f16)oacc[tv][r];
        }
    }
}

// out[o] = sum over 4 n-splits of fp16 partials; 4 outputs/thread, coalesced
__global__ __launch_bounds__(256)
void reduce4h(const f16* __restrict__ ws, float4* __restrict__ out)
{
    const int i = blockIdx.x * 256 + threadIdx.x;    // float4 index, 0..524287
    const int o = i * 4;
    const int m_glob = o & 2047;
    const int vb     = o >> 11;        // v + 128*b
    const int v      = vb & 127;
    const int bb     = vb >> 7;
    const int mt     = m_glob >> 7;
    const int m      = m_glob & 127;
    const size_t base = (size_t)(bb + 8 * mt) * 16384 + (size_t)v * 128 + m;
    const size_t strd = (size_t)128 * 16384;   // 128 blocks per n-split
    float s0 = 0.0f, s1 = 0.0f, s2 = 0.0f, s3 = 0.0f;
    #pragma unroll
    for (int sp = 0; sp < 4; ++sp) {
        const f16x4 h = *(const f16x4*)(ws + base + sp * strd);
        s0 += (float)h[0];
        s1 += (float)h[1];
        s2 += (float)h[2];
        s3 += (float)h[3];
    }
    float4 r; r.x = s0; r.y = s1; r.z = s2; r.w = s3;
    out[i] = r;
}

// ============================================================================
// v1 kernel + reduce4 kept verbatim as fallback for small-ws harnesses
// ============================================================================
__global__ __launch_bounds__(256)
void reduce4(const float4* __restrict__ ws, float4* __restrict__ out)
{
    const int i = blockIdx.x * 256 + threadIdx.x;
    const int o = i * 4;
    const int m_glob = o & 2047;
    const int vb     = o >> 11;
    const int v      = vb & 127;
    const int bb     = vb >> 7;
    const int mt     = m_glob >> 7;
    const int m      = m_glob & 127;
    const size_t base = ((size_t)(bb + 8 * mt) * 16384 + (size_t)v * 128 + m) >> 2;
    const size_t strd = 524288;
    float4 a = ws[base];
    float4 c = ws[base + strd];
    float4 d = ws[base + 2 * strd];
    float4 e = ws[base + 3 * strd];
    float4 r;
    r.x = a.x + c.x + d.x + e.x;
    r.y = a.y + c.y + d.y + e.y;
    r.z = a.z + c.z + d.z + e.z;
    r.w = a.w + c.w + d.w + e.w;
    out[i] = r;
}

template <int WSMODE>
__global__ __launch_bounds__(512, 4)
void sig_attn(const float* __restrict__ Q, const float* __restrict__ K,
              const float* __restrict__ V, float* __restrict__ outp)
{
    __shared__ __align__(16) __bf16 Qs[64 * 128];
    __shared__ __align__(16) __bf16 Ss[128 * 64];
    __shared__ __align__(16) __bf16 Vs[2][128 * 64];

    const int t   = threadIdx.x;
    const int w   = t >> 6;
    const int l   = t & 63;
    const int lq  = l >> 5;
    const int l31 = l & 31;
    const int wm  = w & 3;
    const int wn  = w >> 2;

    const int bid    = blockIdx.x;
    const int b      = bid & 7;
    const int mt     = (bid >> 3) & 15;
    const int ns     = bid >> 7;
    const int m_blk  = mt * 128;
    const int n_base = ns * 512;

    const float* Qb = Q + (size_t)b * DT * NT;
    const float* Kb = K + (size_t)b * DT * NT;
    const float* Vb = V + (size_t)b * DT * NT;

    const int mrow = 32 * wm + l31;

    bf16x8 kf[8];
    #pragma unroll
    for (int half = 0; half < 2; ++half) {
        float tmp[4][8];
        #pragma unroll
        for (int k2 = 0; k2 < 4; ++k2)
            #pragma unroll
            for (int j = 0; j < 8; ++j)
                tmp[k2][j] = Kb[(size_t)((half * 4 + k2) * 16 + lq * 8 + j) * NT + m_blk + mrow];
        #pragma unroll
        for (int k2 = 0; k2 < 4; ++k2) {
            bf16x8 f;
            #pragma unroll
            for (int j = 0; j < 8; ++j) f[j] = (__bf16)tmp[k2][j];
            kf[half * 4 + k2] = f;
        }
    }

    f32x16 oacc[2];
    #pragma unroll
    for (int tv = 0; tv < 2; ++tv)
        #pragma unroll
        for (int r = 0; r < 16; ++r)
            oacc[tv][r] = 0.0f;

    float qp[16];
    #pragma unroll
    for (int r = 0; r < 2; ++r)
        #pragma unroll
        for (int j = 0; j < 8; ++j)
            qp[r * 8 + j] = Qb[(size_t)(64 * r + 8 * w + j) * NT + n_base + l];
    float4 vp[4];
    #pragma unroll
    for (int p = 0; p < 4; ++p)
        vp[p] = *(const float4*)(Vb + (size_t)(p * 32 + (t >> 4)) * NT + n_base + 4 * (t & 15));

    for (int it = 0; it < 8; ++it) {
        __bf16* Vbuf = Vs[it & 1];

        #pragma unroll
        for (int r = 0; r < 2; ++r) {
            bf16x8 pk;
            #pragma unroll
            for (int j = 0; j < 8; ++j) pk[j] = (__bf16)qp[r * 8 + j];
            *(bf16x8*)&Qs[l * 128 + ((8 * r + w) ^ (l & 15)) * 8] = pk;
        }
        #pragma unroll
        for (int p = 0; p < 4; ++p) {
            const int v  = p * 32 + (t >> 4);
            const int ng = t & 15;
            bf16x4 pk;
            pk[0] = (__bf16)vp[p].x;
            pk[1] = (__bf16)vp[p].y;
            pk[2] = (__bf16)vp[p].z;
            pk[3] = (__bf16)vp[p].w;
            *(bf16x4*)&Vbuf[v * 64 + ((ng >> 1) ^ (v & 7)) * 8 + 4 * (ng & 1)] = pk;
        }
        __syncthreads();

        const int n0n = n_base + ((it + 1) & 7) * 64;
        #pragma unroll
        for (int r = 0; r < 2; ++r)
            #pragma unroll
            for (int j = 0; j < 8; ++j)
                qp[r * 8 + j] = Qb[(size_t)(64 * r + 8 * w + j) * NT + n0n + l];
        #pragma unroll
        for (int p = 0; p < 4; ++p)
            vp[p] = *(const float4*)(Vb + (size_t)(p * 32 + (t >> 4)) * NT + n0n + 4 * (t & 15));

        f32x16 sacc;
        #pragma unroll
        for (int r = 0; r < 16; ++r) sacc[r] = 0.0f;
        const int nrow = 32 * wn + l31;
        #pragma unroll
        for (int k = 0; k < 8; ++k) {
            const bf16x8 af =
                *(const bf16x8*)&Qs[nrow * 128 + ((2 * k + lq) ^ (nrow & 15)) * 8];
            sacc = __builtin_amdgcn_mfma_f32_32x32x16_bf16(af, kf[k], sacc, 0, 0, 0);
        }

        #pragma unroll
        for (int g = 0; g < 4; ++g) {
            bf16x4 pk;
            #pragma unroll
            for (int rr = 0; rr < 4; ++rr) {
                const float x = sacc[4 * g + rr];
                const float e = __expf(x * -0.08838834764831845f);
                pk[rr] = (__bf16)__builtin_amdgcn_rcpf(1.0f + e);
            }
            *(bf16x4*)&Ss[mrow * 64 + ((4 * wn + g) ^ (mrow & 7)) * 8 + 4 * lq] = pk;
        }
        __syncthreads();

        #pragma unroll
        for (int k = 0; k < 4; ++k) {
            const int sw = 2 * k + lq;
            const bf16x8 av0 =
                *(const bf16x8*)&Vbuf[(64 * wn + l31) * 64 + (sw ^ (l31 & 7)) * 8];
            const bf16x8 av1 =
                *(const bf16x8*)&Vbuf[(64 * wn + 32 + l31) * 64 + (sw ^ (l31 & 7)) * 8];
            const bf16x8 bs =
                *(const bf16x8*)&Ss[mrow * 64 + (sw ^ (mrow & 7)) * 8];
            oacc[0] = __builtin_amdgcn_mfma_f32_32x32x16_bf16(av0, bs, oacc[0], 0, 0, 0);
            oacc[1] = __builtin_amdgcn_mfma_f32_32x32x16_bf16(av1, bs, oacc[1], 0, 0, 0);
        }
    }

    if (WSMODE == 0) {
        float* wsb = outp + (size_t)bid * 16384;
        #pragma unroll
        for (int tv = 0; tv < 2; ++tv) {
            #pragma unroll
            for (int r = 0; r < 16; ++r) {
                const int v = 64 * wn + 32 * tv + (r & 3) + 8 * (r >> 2) + 4 * lq;
                wsb[v * 128 + mrow] = oacc[tv][r];
            }
        }
    } else {
        float* Ob = outp + (size_t)b * DT * NT;
        #pragma unroll
        for (int tv = 0; tv < 2; ++tv) {
            #pragma unroll
            for (int r = 0; r < 16; ++r) {
                const int v = 64 * wn + 32 * tv + (r & 3) + 8 * (r >> 2) + 4 * lq;
                atomicAdd(&Ob[(size_t)v * NT + m_blk + mrow], oacc[tv][r]);
            }
        }
    }
}

extern "C" void kernel_launch(void* const* d_in, const int* in_sizes, int n_in,
                              void* d_out, int out_size, void* d_ws, size_t ws_size,
                              hipStream_t stream) {
    (void)in_sizes; (void)n_in;
    const float* Q = (const float*)d_in[0];
    const float* K = (const float*)d_in[1];
    const float* V = (const float*)d_in[2];
    const size_t PARTH = (size_t)512 * 16384 * 2;          // 16.8 MB fp16 partials
    const size_t FRAGB = (size_t)2097152 * 2;              // 4 MB per operand buffer
    const size_t PARTF = (size_t)512 * 16384 * 4;          // fallback fp32 partials
    if (ws_size >= PARTH + 3 * FRAGB) {                    // 29.4 MB (ws is 256 MiB)
        __bf16* Qf = (__bf16*)((char*)d_ws + PARTH);
        __bf16* Kf = Qf + 2097152;
        __bf16* Vf = Kf + 2097152;
        prep2<<<dim3(768), dim3(256), 0, stream>>>(Q, K, V, Qf, Kf, Vf);
        sig_attn8h<<<dim3(512), dim3(256), 0, stream>>>(Qf, Kf, Vf, (f16*)d_ws);
        reduce4h<<<dim3(2048), dim3(256), 0, stream>>>((const f16*)d_ws, (float4*)d_out);
    } else if (ws_size >= PARTF) {
        sig_attn<0><<<dim3(512), dim3(512), 0, stream>>>(Q, K, V, (float*)d_ws);
        reduce4<<<dim3(2048), dim3(256), 0, stream>>>((const float4*)d_ws, (float4*)d_out);
    } else {
        hipMemsetAsync(d_out, 0, (size_t)out_size * sizeof(float), stream);
        sig_attn<1><<<dim3(512), dim3(512), 0, stream>>>(Q, K, V, (float*)d_out);
    }
}